// Round 1
// baseline (274.811 us; speedup 1.0000x reference)
//
#include <hip/hip_runtime.h>

// FFF tree-routing MLP, MI355X — fp32 I/O. Round 6: register-starvation fix.
//
// R5 post-mortem: phaseA showed VGPR=48, VALUBusy 17%, HBM 25%, 79us.
// 79us*2.4GHz = 190K cyc at 12.5 waves/CU -> ~74K cyc per token = ~6K cyc
// per level, vs ~700 for one batched row-load + dot + reduce. Root cause:
// default launch_bounds let the compiler allocate 48 VGPRs, which cannot
// hold the 8 w-float4 + 8 x-float4 working set -> the dot was compiled as
// serial register-starved sub-batches (4+ dependent memory latencies per
// level). Fix: __launch_bounds__(256,4) (cap 128 VGPR, still 16 waves/CU)
// + explicit wv[8] batch-load before consumption.
// Structural: (a) grid-fuse the independent w_out transpose into the phaseA
// dispatch (odd blocks) so its BW work fills phaseA's latency bubbles;
// (b) drop init/scan/scatter: phaseB blocks scan the 32KB L2-hot leaf[]
// array directly and build their token list in LDS (8192-entry, no overflow
// possible). 6 dispatches -> 2. All FP accumulation orders bit-identical
// to the previous passing kernel.

#define D_IN    2048
#define D_OUT   2048
#define DEPTHP1 12
#define N_NODES 4095
#define N_TOK   8192
#define N_LEAF  2048

// ---------------- K1: fused transpose (odd blocks) + phaseA (even blocks) --
__global__ __launch_bounds__(256, 4) void fusedA(
    const float* __restrict__ x,       // [N_TOK, D_IN]
    const float* __restrict__ w_in,    // [N_NODES, D_IN]
    const float* __restrict__ w_out,   // [D_OUT, N_NODES]
    float* __restrict__ w_out_t,       // [N_NODES, D_OUT]
    float* __restrict__ g_all,         // [N_TOK, 12]
    int* __restrict__ leaf) {          // [N_TOK]
    extern __shared__ char smem[];     // 32 KB dynamic, aliased by both paths

    if (blockIdx.x & 1) {
        // ---- transpose tile: w_out[j][n] -> w_out_t[n][j] ----
        float (*tile)[65] = (float(*)[65])smem;   // 64x65 = 16.64 KB
        const int tb = blockIdx.x >> 1;           // 0..2047
        const int n0 = (tb & 63) * 64;
        const int j0 = (tb >> 6) * 64;
        const int tx = threadIdx.x & 63;
        const int ty = threadIdx.x >> 6;
        const int n = n0 + tx;
#pragma unroll
        for (int k = 0; k < 16; k++) {
            const int r = ty * 16 + k;            // 0..63
            if (n < N_NODES) tile[r][tx] = w_out[(size_t)(j0 + r) * N_NODES + n];
        }
        __syncthreads();
#pragma unroll
        for (int k = 0; k < 16; k++) {
            const int r = ty * 16 + k;
            const int nn = n0 + r;
            if (nn < N_NODES) w_out_t[(size_t)nn * D_OUT + (j0 + tx)] = tile[tx][r];
        }
        return;
    }

    // ---- phaseA: tree descent, one wave per token, x staged in LDS ----
    float* xs = (float*)smem;                     // 4 waves x 2048 f32 = 32 KB
    const int wave  = threadIdx.x >> 6;
    const int lane  = threadIdx.x & 63;
    const int token = (blockIdx.x >> 1) * 4 + wave;

    float4* xw = (float4*)xs + wave * (D_IN / 4);
    const float4* xrow = (const float4*)(x + (size_t)token * D_IN);
#pragma unroll
    for (int c = 0; c < 8; c++) xw[lane + 64 * c] = xrow[lane + 64 * c];
    // Same-wave produce->consume; compiler inserts lgkmcnt wait. No barrier.

    int cur = 0;
#pragma unroll
    for (int l = 0; l < DEPTHP1; l++) {
        const float4* wrow = (const float4*)(w_in + (size_t)cur * D_IN);
        // Batch ALL 8 row loads first: one memory latency per level, not 4+.
        float4 wv[8];
#pragma unroll
        for (int c = 0; c < 8; c++) wv[c] = wrow[lane + 64 * c];
        float p0 = 0.f, p1 = 0.f, p2 = 0.f, p3 = 0.f;
#pragma unroll
        for (int c = 0; c < 8; c++) {
            const float4 xc = xw[lane + 64 * c];
            float* p = (c < 2) ? &p0 : (c < 4) ? &p1 : (c < 6) ? &p2 : &p3;
            *p += wv[c].x * xc.x + wv[c].y * xc.y + wv[c].z * xc.z + wv[c].w * xc.w;
        }
        float part = (p0 + p1) + (p2 + p3);
#pragma unroll
        for (int off = 32; off >= 1; off >>= 1)
            part += __shfl_xor(part, off, 64);
        const float score = part;
        // Advance the path first: next-level loads depend only on `cur`.
        cur = 2 * cur + 1 + (score >= 0.f ? 1 : 0);
        const float g = 0.5f * score * (1.0f + erff(score * 0.70710678118654752f));
        if (lane == 0) g_all[token * DEPTHP1 + l] = g;
    }
    if (lane == 0) leaf[token] = ((cur - 1) >> 1) - (N_LEAF - 1);
}

// ---------------- K2: phase B — direct leaf scan + output accumulation -----
__global__ __launch_bounds__(256, 2) void phaseB2(
    const float* __restrict__ w_out_t,  // [N_NODES, D_OUT]
    const float* __restrict__ g_all,    // [N_TOK, 12]
    const int* __restrict__ leaf,       // [N_TOK]
    float* __restrict__ out) {          // [N_TOK, D_OUT]
    // XCD swizzle: XCD k (= blockIdx%8) gets contiguous leaves [k*256,(k+1)*256)
    const int lf = ((blockIdx.x & 7) << 8) | (blockIdx.x >> 3);
    __shared__ int toks[N_TOK];          // 32 KB: overflow impossible
    __shared__ int lcount;
    const int t = threadIdx.x;           // owns output cols [8t, 8t+8)
    if (t == 0) lcount = 0;
    __syncthreads();
    // leaf[] is 32 KB and L2-hot across all 2048 blocks: scan it directly.
#pragma unroll
    for (int k = 0; k < N_TOK / 256; k++) {
        const int tok = k * 256 + t;
        if (leaf[tok] == lf) toks[atomicAdd(&lcount, 1)] = tok;
    }
    __syncthreads();
    const int n = lcount;
    if (n == 0) return;

    int nodes[DEPTHP1];
    const int L = lf + N_LEAF;           // 1-based leaf heap index
#pragma unroll
    for (int l = 0; l < DEPTHP1; l++) nodes[l] = (L >> (DEPTHP1 - 1 - l)) - 1;

    for (int cs = 0; cs < n; cs += 8) {
        const int T = n - cs;            // effective count this chunk: min(T,8)
        float acc[8][8];
#pragma unroll
        for (int tt = 0; tt < 8; tt++)
#pragma unroll
            for (int k = 0; k < 8; k++) acc[tt][k] = 0.f;

#pragma unroll
        for (int l = 0; l < DEPTHP1; l++) {
            const float4* wr = (const float4*)(w_out_t + (size_t)nodes[l] * D_OUT);
            const float4 w0 = wr[t * 2 + 0];
            const float4 w1 = wr[t * 2 + 1];
#pragma unroll
            for (int tt = 0; tt < 8; tt++) {
                const float g = (tt < T)
                    ? g_all[(size_t)toks[cs + tt] * DEPTHP1 + l] : 0.f;
                acc[tt][0] += g * w0.x; acc[tt][1] += g * w0.y;
                acc[tt][2] += g * w0.z; acc[tt][3] += g * w0.w;
                acc[tt][4] += g * w1.x; acc[tt][5] += g * w1.y;
                acc[tt][6] += g * w1.z; acc[tt][7] += g * w1.w;
            }
        }
#pragma unroll
        for (int tt = 0; tt < 8; tt++) {
            if (tt < T) {
                const int tok = toks[cs + tt];
                float4* po = (float4*)(out + (size_t)tok * D_OUT + t * 8);
                float4 o0, o1;
                o0.x = acc[tt][0]; o0.y = acc[tt][1];
                o0.z = acc[tt][2]; o0.w = acc[tt][3];
                o1.x = acc[tt][4]; o1.y = acc[tt][5];
                o1.z = acc[tt][6]; o1.w = acc[tt][7];
                po[0] = o0; po[1] = o1;
            }
        }
    }
}

// ---------------- Fallback kernels (small workspace) -----------------------
__global__ __launch_bounds__(256) void transpose_wout64(
    const float* __restrict__ in, float* __restrict__ out) {
    __shared__ float tile[64][65];
    const int n0 = blockIdx.x * 64;
    const int j0 = blockIdx.y * 64;
    const int tx = threadIdx.x;
    const int ty = threadIdx.y;
    const int n = n0 + tx;
#pragma unroll
    for (int k = 0; k < 16; k++) {
        const int r = ty * 16 + k;
        if (n < N_NODES) tile[r][tx] = in[(size_t)(j0 + r) * N_NODES + n];
    }
    __syncthreads();
#pragma unroll
    for (int k = 0; k < 16; k++) {
        const int r = ty * 16 + k;
        const int nn = n0 + r;
        if (nn < N_NODES) out[(size_t)nn * D_OUT + (j0 + tx)] = tile[tx][r];
    }
}

template <bool TRANSPOSED>
__global__ __launch_bounds__(256) void fff_fused(
    const float* __restrict__ x, const float* __restrict__ w_in,
    const float* __restrict__ w_out, float* __restrict__ out) {
    const int wave  = threadIdx.x >> 6;
    const int lane  = threadIdx.x & 63;
    const int token = blockIdx.x * 4 + wave;
    const float4* xrow = (const float4*)(x + (size_t)token * D_IN);
    float xf[32];
#pragma unroll
    for (int c = 0; c < 8; c++) {
        float4 xc = xrow[lane + 64 * c];
        xf[c * 4 + 0] = xc.x; xf[c * 4 + 1] = xc.y;
        xf[c * 4 + 2] = xc.z; xf[c * 4 + 3] = xc.w;
    }
    float acc[32];
#pragma unroll
    for (int k = 0; k < 32; k++) acc[k] = 0.f;
    int cur = 0;
#pragma unroll
    for (int l = 0; l < DEPTHP1; l++) {
        const float4* wrow = (const float4*)(w_in + (size_t)cur * D_IN);
        float part = 0.f;
#pragma unroll
        for (int c = 0; c < 8; c++) {
            float4 wc = wrow[lane + 64 * c];
            part += wc.x * xf[c * 4 + 0]; part += wc.y * xf[c * 4 + 1];
            part += wc.z * xf[c * 4 + 2]; part += wc.w * xf[c * 4 + 3];
        }
#pragma unroll
        for (int off = 32; off >= 1; off >>= 1) part += __shfl_xor(part, off, 64);
        const float score = part;
        const float g = 0.5f * score * (1.0f + erff(score * 0.70710678118654752f));
        if (TRANSPOSED) {
            const float4* orow = (const float4*)(w_out + (size_t)cur * D_OUT);
#pragma unroll
            for (int c = 0; c < 8; c++) {
                float4 oc = orow[lane + 64 * c];
                acc[c * 4 + 0] += g * oc.x; acc[c * 4 + 1] += g * oc.y;
                acc[c * 4 + 2] += g * oc.z; acc[c * 4 + 3] += g * oc.w;
            }
        } else {
#pragma unroll
            for (int c = 0; c < 8; c++)
#pragma unroll
                for (int k = 0; k < 4; k++) {
                    const int j = (lane + 64 * c) * 4 + k;
                    acc[c * 4 + k] += g * w_out[(size_t)j * N_NODES + cur];
                }
        }
        cur = 2 * cur + 1 + (score >= 0.f ? 1 : 0);
    }
    float4* outrow = (float4*)(out + (size_t)token * D_OUT);
#pragma unroll
    for (int c = 0; c < 8; c++) {
        float4 o;
        o.x = acc[c * 4 + 0]; o.y = acc[c * 4 + 1];
        o.z = acc[c * 4 + 2]; o.w = acc[c * 4 + 3];
        outrow[lane + 64 * c] = o;
    }
}

extern "C" void kernel_launch(void* const* d_in, const int* in_sizes, int n_in,
                              void* d_out, int out_size, void* d_ws, size_t ws_size,
                              hipStream_t stream) {
    (void)in_sizes; (void)n_in; (void)out_size;
    const float* x     = (const float*)d_in[0];
    const float* w_in  = (const float*)d_in[1];
    const float* w_out = (const float*)d_in[2];
    float* out = (float*)d_out;

    const size_t wt_bytes   = (size_t)N_NODES * D_OUT * sizeof(float);   // 33.546 MB
    const size_t g_bytes    = (size_t)N_TOK * DEPTHP1 * sizeof(float);   // 393 KB
    const size_t leaf_bytes = (size_t)N_TOK * sizeof(int);               // 32 KB
    const size_t need = wt_bytes + g_bytes + leaf_bytes + 64;

    if (ws_size >= need) {
        char* p = (char*)d_ws;
        float* w_out_t = (float*)p;  p += wt_bytes;
        float* g_all   = (float*)p;  p += g_bytes;
        int*   leaf    = (int*)p;

        // Even blocks: phaseA (2048 token-quads). Odd blocks: transpose (2048 tiles).
        fusedA<<<4096, 256, 4 * D_IN * sizeof(float), stream>>>(
            x, w_in, w_out, w_out_t, g_all, leaf);
        phaseB2<<<N_LEAF, 256, 0, stream>>>(w_out_t, g_all, leaf, out);
    } else if (ws_size >= wt_bytes) {
        float* w_out_t = (float*)d_ws;
        transpose_wout64<<<dim3((N_NODES + 63) / 64, D_OUT / 64), dim3(64, 4),
                           0, stream>>>(w_out, w_out_t);
        fff_fused<true><<<N_TOK / 4, 256, 0, stream>>>(x, w_in, w_out_t, out);
    } else {
        fff_fused<false><<<N_TOK / 4, 256, 0, stream>>>(x, w_in, w_out, out);
    }
}

// Round 2
// 261.192 us; speedup vs baseline: 1.0521x; 1.0521x over previous
//
#include <hip/hip_runtime.h>

// FFF tree-routing MLP, MI355X — fp32 I/O. Round 7: erf eviction + reg-x.
//
// R6 post-mortem: VGPR stayed 48 even with a 128 cap -> the compiler CHOOSES
// to rematerialize; suspect the erff() OCML call in the level loop. Occupancy
// fell 39->24% (32KB dynamic LDS charged to every fused block + min-waves
// hint). phaseB2's in-block leaf scan + 32KB toks[] regressed phaseB ~30us.
// R7: (1) phaseA stores RAW scores; gelu moves to scatter_tokens (12 erf per
// token total, off every critical path). (2) x lives in float4 xf[8] regs,
// zero LDS in the phaseA path; fused kernel's only LDS is the transpose's
// static 16.6KB tile. Plain launch_bounds(256). (3) phaseB reverts to the
// global scatter machinery (no 32KB toks, no per-block scan), hoists all 24
// w-row float4 loads out of the chunk loop, and stages each chunk's 96 g
// values + 8 order entries in LDS. All FP accumulation/reduction orders are
// bit-identical to the R5/R6 passing kernels (path-flip hazard).

#define D_IN    2048
#define D_OUT   2048
#define DEPTHP1 12
#define N_NODES 4095
#define N_TOK   8192
#define N_LEAF  2048

// ---------------- K1: fused transpose (odd blocks) + phaseA (even blocks) --
__global__ __launch_bounds__(256) void fusedA2(
    const float* __restrict__ x,       // [N_TOK, D_IN]
    const float* __restrict__ w_in,    // [N_NODES, D_IN]
    const float* __restrict__ w_out,   // [D_OUT, N_NODES]
    float* __restrict__ w_out_t,       // [N_NODES, D_OUT]
    float* __restrict__ s_all,         // [N_TOK, 12] RAW scores
    int* __restrict__ leaf,            // [N_TOK]
    int* __restrict__ hist) {          // [N_LEAF]
    if (blockIdx.x & 1) {
        // ---- transpose tile: w_out[j][n] -> w_out_t[n][j] ----
        __shared__ float tile[64][65];            // 16.64 KB static
        const int tb = blockIdx.x >> 1;           // 0..2047
        const int n0 = (tb & 63) * 64;
        const int j0 = (tb >> 6) * 64;
        const int tx = threadIdx.x & 63;
        const int ty = threadIdx.x >> 6;
        const int n = n0 + tx;
#pragma unroll
        for (int k = 0; k < 16; k++) {
            const int r = ty * 16 + k;            // 0..63
            if (n < N_NODES) tile[r][tx] = w_out[(size_t)(j0 + r) * N_NODES + n];
        }
        __syncthreads();
#pragma unroll
        for (int k = 0; k < 16; k++) {
            const int r = ty * 16 + k;
            const int nn = n0 + r;
            if (nn < N_NODES) w_out_t[(size_t)nn * D_OUT + (j0 + tx)] = tile[tx][r];
        }
        return;
    }

    // ---- phaseA: tree descent, one wave per token, x in REGISTERS ----
    const int wave  = threadIdx.x >> 6;
    const int lane  = threadIdx.x & 63;
    const int token = (blockIdx.x >> 1) * 4 + wave;

    const float4* xrow = (const float4*)(x + (size_t)token * D_IN);
    float4 xf[8];
#pragma unroll
    for (int c = 0; c < 8; c++) xf[c] = xrow[lane + 64 * c];

    int cur = 0;
#pragma unroll
    for (int l = 0; l < DEPTHP1; l++) {
        const float4* wrow = (const float4*)(w_in + (size_t)cur * D_IN);
        // Batch ALL 8 row loads: one memory latency per level.
        float4 wv[8];
#pragma unroll
        for (int c = 0; c < 8; c++) wv[c] = wrow[lane + 64 * c];
        float p0 = 0.f, p1 = 0.f, p2 = 0.f, p3 = 0.f;
#pragma unroll
        for (int c = 0; c < 8; c++) {
            float* p = (c < 2) ? &p0 : (c < 4) ? &p1 : (c < 6) ? &p2 : &p3;
            *p += wv[c].x * xf[c].x + wv[c].y * xf[c].y +
                  wv[c].z * xf[c].z + wv[c].w * xf[c].w;
        }
        float part = (p0 + p1) + (p2 + p3);
#pragma unroll
        for (int off = 32; off >= 1; off >>= 1)
            part += __shfl_xor(part, off, 64);
        const float score = part;
        cur = 2 * cur + 1 + (score >= 0.f ? 1 : 0);
        if (lane == 0) s_all[token * DEPTHP1 + l] = score;  // raw; gelu later
    }
    if (lane == 0) {
        const int leafid = ((cur - 1) >> 1) - (N_LEAF - 1);
        leaf[token] = leafid;
        atomicAdd(&hist[leafid], 1);
    }
}

// ---------------- K2: zero hist + cnt (contiguous 2*N_LEAF ints) -----------
__global__ __launch_bounds__(256) void init_counts(int* __restrict__ p) {
    const int i = blockIdx.x * 256 + threadIdx.x;
    if (i < 2 * N_LEAF) p[i] = 0;
}

// ---------------- K3: exclusive scan over 2048 bins ------------------------
__global__ __launch_bounds__(256) void scan2048(
    const int* __restrict__ hist, int* __restrict__ offsets /*[2049]*/) {
    __shared__ int vals[N_LEAF];
    __shared__ int partial[256];
    const int t = threadIdx.x;
    int sum = 0;
#pragma unroll
    for (int k = 0; k < 8; k++) {
        const int v = hist[t * 8 + k];
        vals[t * 8 + k] = v;
        sum += v;
    }
    partial[t] = sum;
    __syncthreads();
    for (int off = 1; off < 256; off <<= 1) {
        const int v  = partial[t];
        const int vo = (t >= off) ? partial[t - off] : 0;
        __syncthreads();
        partial[t] = v + vo;
        __syncthreads();
    }
    int base = (t > 0) ? partial[t - 1] : 0;
#pragma unroll
    for (int k = 0; k < 8; k++) {
        offsets[t * 8 + k] = base;
        base += vals[t * 8 + k];
    }
    if (t == 255) offsets[N_LEAF] = base;  // == N_TOK
}

// ---------------- K4: scatter tokens; apply gelu HERE ----------------------
__global__ __launch_bounds__(256) void scatter_tokens2(
    const int* __restrict__ leaf, const int* __restrict__ offsets,
    int* __restrict__ cnt, const float* __restrict__ s_all,
    int* __restrict__ order, float* __restrict__ g_sorted) {
    const int t = blockIdx.x * 256 + threadIdx.x;
    if (t < N_TOK) {
        const int lf = leaf[t];
        const int pos = offsets[lf] + atomicAdd(&cnt[lf], 1);
        order[pos] = t;
#pragma unroll
        for (int l = 0; l < DEPTHP1; l++) {
            const float s = s_all[(size_t)t * DEPTHP1 + l];
            const float g = 0.5f * s * (1.0f + erff(s * 0.70710678118654752f));
            g_sorted[(size_t)pos * DEPTHP1 + l] = g;
        }
    }
}

// ---------------- K5: phase B — leaf-grouped output accumulation -----------
__global__ __launch_bounds__(256, 2) void phaseB3(
    const float* __restrict__ w_out_t,  // [N_NODES, D_OUT]
    const float* __restrict__ g_sorted, // [N_TOK, 12] leaf-sorted, gelu'd
    const int* __restrict__ order,      // [N_TOK]
    const int* __restrict__ offsets,    // [N_LEAF+1]
    float* __restrict__ out) {          // [N_TOK, D_OUT]
    // XCD swizzle: XCD k (= blockIdx%8) gets contiguous leaves [k*256,(k+1)*256)
    const int lf = ((blockIdx.x & 7) << 8) | (blockIdx.x >> 3);
    const int start = offsets[lf];
    const int end   = offsets[lf + 1];
    if (start == end) return;
    const int t = threadIdx.x;           // owns cols [8t, 8t+8)

    __shared__ float gs[96];             // chunk's 8 tokens x 12 levels
    __shared__ int   ord[8];

    int nodes[DEPTHP1];
    const int L = lf + N_LEAF;           // 1-based leaf heap index
#pragma unroll
    for (int l = 0; l < DEPTHP1; l++) nodes[l] = (L >> (DEPTHP1 - 1 - l)) - 1;

    // Path is fixed per block: hoist ALL 24 w float4 loads out of chunk loop.
    float4 w0[DEPTHP1], w1[DEPTHP1];
#pragma unroll
    for (int l = 0; l < DEPTHP1; l++) {
        const float4* wr = (const float4*)(w_out_t + (size_t)nodes[l] * D_OUT);
        w0[l] = wr[t * 2 + 0];
        w1[l] = wr[t * 2 + 1];
    }

    for (int cs = start; cs < end; cs += 8) {
        const int T = end - cs;          // effective count this chunk: min(T,8)
        __syncthreads();                 // protect gs/ord across chunks
        if (t < 96 && (size_t)cs * 12 + t < (size_t)end * 12)
            gs[t] = g_sorted[(size_t)cs * 12 + t];
        if (t >= 96 && t < 104 && cs + (t - 96) < end)
            ord[t - 96] = order[cs + (t - 96)];
        __syncthreads();

        float acc[8][8];
#pragma unroll
        for (int tt = 0; tt < 8; tt++)
#pragma unroll
            for (int k = 0; k < 8; k++) acc[tt][k] = 0.f;

#pragma unroll
        for (int l = 0; l < DEPTHP1; l++) {
#pragma unroll
            for (int tt = 0; tt < 8; tt++) {
                const float g = (tt < T) ? gs[tt * DEPTHP1 + l] : 0.f;
                acc[tt][0] += g * w0[l].x; acc[tt][1] += g * w0[l].y;
                acc[tt][2] += g * w0[l].z; acc[tt][3] += g * w0[l].w;
                acc[tt][4] += g * w1[l].x; acc[tt][5] += g * w1[l].y;
                acc[tt][6] += g * w1[l].z; acc[tt][7] += g * w1[l].w;
            }
        }
#pragma unroll
        for (int tt = 0; tt < 8; tt++) {
            if (tt < T) {
                const int tok = ord[tt];
                float4* po = (float4*)(out + (size_t)tok * D_OUT + t * 8);
                float4 o0, o1;
                o0.x = acc[tt][0]; o0.y = acc[tt][1];
                o0.z = acc[tt][2]; o0.w = acc[tt][3];
                o1.x = acc[tt][4]; o1.y = acc[tt][5];
                o1.z = acc[tt][6]; o1.w = acc[tt][7];
                po[0] = o0; po[1] = o1;
            }
        }
    }
}

// ---------------- Fallback kernels (small workspace) -----------------------
__global__ __launch_bounds__(256) void transpose_wout64(
    const float* __restrict__ in, float* __restrict__ out) {
    __shared__ float tile[64][65];
    const int n0 = blockIdx.x * 64;
    const int j0 = blockIdx.y * 64;
    const int tx = threadIdx.x;
    const int ty = threadIdx.y;
    const int n = n0 + tx;
#pragma unroll
    for (int k = 0; k < 16; k++) {
        const int r = ty * 16 + k;
        if (n < N_NODES) tile[r][tx] = in[(size_t)(j0 + r) * N_NODES + n];
    }
    __syncthreads();
#pragma unroll
    for (int k = 0; k < 16; k++) {
        const int r = ty * 16 + k;
        const int nn = n0 + r;
        if (nn < N_NODES) out[(size_t)nn * D_OUT + (j0 + tx)] = tile[tx][r];
    }
}

template <bool TRANSPOSED>
__global__ __launch_bounds__(256) void fff_fused(
    const float* __restrict__ x, const float* __restrict__ w_in,
    const float* __restrict__ w_out, float* __restrict__ out) {
    const int wave  = threadIdx.x >> 6;
    const int lane  = threadIdx.x & 63;
    const int token = blockIdx.x * 4 + wave;
    const float4* xrow = (const float4*)(x + (size_t)token * D_IN);
    float xf[32];
#pragma unroll
    for (int c = 0; c < 8; c++) {
        float4 xc = xrow[lane + 64 * c];
        xf[c * 4 + 0] = xc.x; xf[c * 4 + 1] = xc.y;
        xf[c * 4 + 2] = xc.z; xf[c * 4 + 3] = xc.w;
    }
    float acc[32];
#pragma unroll
    for (int k = 0; k < 32; k++) acc[k] = 0.f;
    int cur = 0;
#pragma unroll
    for (int l = 0; l < DEPTHP1; l++) {
        const float4* wrow = (const float4*)(w_in + (size_t)cur * D_IN);
        float part = 0.f;
#pragma unroll
        for (int c = 0; c < 8; c++) {
            float4 wc = wrow[lane + 64 * c];
            part += wc.x * xf[c * 4 + 0]; part += wc.y * xf[c * 4 + 1];
            part += wc.z * xf[c * 4 + 2]; part += wc.w * xf[c * 4 + 3];
        }
#pragma unroll
        for (int off = 32; off >= 1; off >>= 1) part += __shfl_xor(part, off, 64);
        const float score = part;
        const float g = 0.5f * score * (1.0f + erff(score * 0.70710678118654752f));
        if (TRANSPOSED) {
            const float4* orow = (const float4*)(w_out + (size_t)cur * D_OUT);
#pragma unroll
            for (int c = 0; c < 8; c++) {
                float4 oc = orow[lane + 64 * c];
                acc[c * 4 + 0] += g * oc.x; acc[c * 4 + 1] += g * oc.y;
                acc[c * 4 + 2] += g * oc.z; acc[c * 4 + 3] += g * oc.w;
            }
        } else {
#pragma unroll
            for (int c = 0; c < 8; c++)
#pragma unroll
                for (int k = 0; k < 4; k++) {
                    const int j = (lane + 64 * c) * 4 + k;
                    acc[c * 4 + k] += g * w_out[(size_t)j * N_NODES + cur];
                }
        }
        cur = 2 * cur + 1 + (score >= 0.f ? 1 : 0);
    }
    float4* outrow = (float4*)(out + (size_t)token * D_OUT);
#pragma unroll
    for (int c = 0; c < 8; c++) {
        float4 o;
        o.x = acc[c * 4 + 0]; o.y = acc[c * 4 + 1];
        o.z = acc[c * 4 + 2]; o.w = acc[c * 4 + 3];
        outrow[lane + 64 * c] = o;
    }
}

extern "C" void kernel_launch(void* const* d_in, const int* in_sizes, int n_in,
                              void* d_out, int out_size, void* d_ws, size_t ws_size,
                              hipStream_t stream) {
    (void)in_sizes; (void)n_in; (void)out_size;
    const float* x     = (const float*)d_in[0];
    const float* w_in  = (const float*)d_in[1];
    const float* w_out = (const float*)d_in[2];
    float* out = (float*)d_out;

    const size_t wt_bytes   = (size_t)N_NODES * D_OUT * sizeof(float);   // 33.546 MB
    const size_t g_bytes    = (size_t)N_TOK * DEPTHP1 * sizeof(float);   // 393 KB
    const size_t leaf_bytes = (size_t)N_TOK * sizeof(int);
    const size_t ord_bytes  = (size_t)N_TOK * sizeof(int);
    const size_t hist_bytes = (size_t)N_LEAF * sizeof(int);
    const size_t cnt_bytes  = (size_t)N_LEAF * sizeof(int);
    const size_t offs_bytes = (size_t)(N_LEAF + 1) * sizeof(int);
    const size_t gs_bytes   = g_bytes;                                   // g_sorted
    const size_t need = wt_bytes + g_bytes + leaf_bytes + ord_bytes +
                        hist_bytes + cnt_bytes + offs_bytes + gs_bytes + 64;

    if (ws_size >= need) {
        char* p = (char*)d_ws;
        float* w_out_t  = (float*)p;  p += wt_bytes;
        float* s_all    = (float*)p;  p += g_bytes;
        int*   leaf     = (int*)p;    p += leaf_bytes;
        int*   order    = (int*)p;    p += ord_bytes;
        int*   hist     = (int*)p;    p += hist_bytes;   // hist+cnt contiguous
        int*   cnt      = (int*)p;    p += cnt_bytes;
        int*   offsets  = (int*)p;    p += offs_bytes;
        float* g_sorted = (float*)p;

        init_counts<<<(2 * N_LEAF + 255) / 256, 256, 0, stream>>>(hist);
        // Even blocks: phaseA (2048 token-quads). Odd blocks: transpose tiles.
        fusedA2<<<4096, 256, 0, stream>>>(x, w_in, w_out, w_out_t,
                                          s_all, leaf, hist);
        scan2048<<<1, 256, 0, stream>>>(hist, offsets);
        scatter_tokens2<<<N_TOK / 256, 256, 0, stream>>>(leaf, offsets, cnt,
                                                         s_all, order, g_sorted);
        phaseB3<<<N_LEAF, 256, 0, stream>>>(w_out_t, g_sorted, order, offsets, out);
    } else if (ws_size >= wt_bytes) {
        float* w_out_t = (float*)d_ws;
        transpose_wout64<<<dim3((N_NODES + 63) / 64, D_OUT / 64), dim3(64, 4),
                           0, stream>>>(w_out, w_out_t);
        fff_fused<true><<<N_TOK / 4, 256, 0, stream>>>(x, w_in, w_out_t, out);
    } else {
        fff_fused<false><<<N_TOK / 4, 256, 0, stream>>>(x, w_in, w_out, out);
    }
}